// Round 9
// baseline (123.076 us; speedup 1.0000x reference)
//
#include <hip/hip_runtime.h>
#include <hip/hip_bf16.h>

#define B_ROWS 4096
#define NROWS  8192   // 2B
#define D      256
#define NSEG   32     // segments per strip-pair
#define NBLK2  1024   // 32 pairs * 32 segments = 4 blocks/CU
#define TPP    130    // 64-col tiles per strip-pair

typedef __attribute__((ext_vector_type(4))) float floatx4;

// ---------------------------------------------------------------------------
// Kernel 1: normalize -> fp8 e4m3 z (2 MiB), exact fp32 pos, zero-inits.
// (validated in R8: absmax 0.0)
// ---------------------------------------------------------------------------
__global__ __launch_bounds__(256) void norm_pos_kernel(
    const float* __restrict__ xi, const float* __restrict__ xj,
    unsigned char* __restrict__ z, float* __restrict__ pos,
    float* __restrict__ rowsum, float* __restrict__ out,
    unsigned int* __restrict__ counter) {
    int gt = blockIdx.x * 256 + threadIdx.x;
    if (gt < NROWS) rowsum[gt] = 0.f;
    if (gt == 0) { out[0] = 0.f; counter[0] = 0u; }

    int p    = blockIdx.x * 4 + (threadIdx.x >> 6);
    int lane = threadIdx.x & 63;
    float4 v1 = ((const float4*)(xi + (size_t)p * D))[lane];
    float4 v2 = ((const float4*)(xj + (size_t)p * D))[lane];
    float ss1 = v1.x * v1.x + v1.y * v1.y + v1.z * v1.z + v1.w * v1.w;
    float ss2 = v2.x * v2.x + v2.y * v2.y + v2.z * v2.z + v2.w * v2.w;
#pragma unroll
    for (int off = 32; off > 0; off >>= 1) {
        ss1 += __shfl_xor(ss1, off);
        ss2 += __shfl_xor(ss2, off);
    }
    float sc1 = 1.0f / fmaxf(sqrtf(ss1), 1e-12f);
    float sc2 = 1.0f / fmaxf(sqrtf(ss2), 1e-12f);

    float n1x = v1.x * sc1, n1y = v1.y * sc1, n1z = v1.z * sc1, n1w = v1.w * sc1;
    float n2x = v2.x * sc2, n2y = v2.y * sc2, n2z = v2.z * sc2, n2w = v2.w * sc2;

    float dp = n1x * n2x + n1y * n2y + n1z * n2z + n1w * n2w;
#pragma unroll
    for (int off = 32; off > 0; off >>= 1) dp += __shfl_xor(dp, off);
    if (lane == 0) { pos[p] = dp; pos[p + B_ROWS] = dp; }

    int q1 = __builtin_amdgcn_cvt_pk_fp8_f32(n1x, n1y, 0, false);
    q1     = __builtin_amdgcn_cvt_pk_fp8_f32(n1z, n1w, q1, true);
    int q2 = __builtin_amdgcn_cvt_pk_fp8_f32(n2x, n2y, 0, false);
    q2     = __builtin_amdgcn_cvt_pk_fp8_f32(n2z, n2w, q2, true);
    ((int*)(z + (size_t)p * D))[lane]            = q1;
    ((int*)(z + (size_t)(p + B_ROWS) * D))[lane] = q2;
}

// ---------------------------------------------------------------------------
// Kernel 2: symmetric sim+exp+rowsum, fp8 MFMA.
// 128-row strips; strip-pair (s, 63-s); 64-col tiles, 130 per pair, 32 segs.
// Wave tile 32x64: A = 32 rows x 256 K fp8 = 32 VGPRs (truly resident),
// acc[2][4] = 32 VGPRs. B tile 64 cols x 256 K = 16 KB, double-buffered LDS,
// layout unit u = c16*64 + col (16B units; c16 = k/16):
//   staging: lane t -> col=t>>2, 16B at part*16+j*64 (4 consecutive lanes =
//     one 64B line, coalesced); ds_write_b128 phase-balanced (2-way, free).
//   frag read: b64 at u=(kk*2+(lg>>1))*64 + col, byte half=(lg&1)*8 ->
//     16 lanes stride 16B = 2-way (free).
// Diag tiles (cloc<2) cover the full 128x128 square: row==col zeroed, no
// mirror. Off-diag: col-sums (mirror) via xor16/32 shuffles + atomics.
// ---------------------------------------------------------------------------
__global__ __launch_bounds__(256, 4) void sim_rowsum_kernel(
    const unsigned char* __restrict__ z, float* __restrict__ rowsum,
    const float* __restrict__ pos, unsigned int* __restrict__ counter,
    float* __restrict__ out) {
    __shared__ __align__(16) int4 Bbuf[2][1024];   // 2 x 16 KB
    __shared__ unsigned int done_s;
    __shared__ float sdata[4];

    const int tid  = threadIdx.x;
    const int lane = tid & 63;
    const int w    = tid >> 6;
    const int lm   = lane & 15;
    const int lg   = lane >> 4;

    const int s  = blockIdx.x >> 5;         // strip-pair 0..31
    const int q  = blockIdx.x & 31;         // segment
    const int L0 = 128 - 2 * s;             // tiles in strip s
    const int cb = (q * TPP) >> 5;
    const int ce = ((q + 1) * TPP) >> 5;

    // staging geometry
    const int scol  = tid >> 2;             // 0..63
    const int spart = tid & 3;

    long long a[8][2];                      // A: 32 rows x 256 K fp8
    floatx4 acc[2][4];
    float rsacc[2][4];
    int4 pf[4];

#pragma unroll
    for (int mi = 0; mi < 2; mi++)
#pragma unroll
        for (int r = 0; r < 4; r++) rsacc[mi][r] = 0.f;

    auto decode = [&](int c, int& strip, int& colbase, int& cloc) {
        if (c < L0) { strip = s;      cloc = c; }
        else        { strip = 63 - s; cloc = c - L0; }
        colbase = strip * 128 + cloc * 64;
    };

    auto loadA = [&](int strip) {
#pragma unroll
        for (int kk = 0; kk < 8; kk++)
#pragma unroll
            for (int mi = 0; mi < 2; mi++)
                a[kk][mi] = *(const long long*)(
                    z + (size_t)(strip * 128 + w * 32 + mi * 16 + lm) * D +
                    kk * 32 + lg * 8);
    };

    auto flushRs = [&](int strip) {
#pragma unroll
        for (int mi = 0; mi < 2; mi++)
#pragma unroll
            for (int r = 0; r < 4; r++) {
                float v = rsacc[mi][r];
                v += __shfl_xor(v, 1); v += __shfl_xor(v, 2);
                v += __shfl_xor(v, 4); v += __shfl_xor(v, 8);
                if (lm == 0)
                    atomicAdd(&rowsum[strip * 128 + w * 32 + mi * 16 + lg * 4 + r], v);
                rsacc[mi][r] = 0.f;
            }
    };

    auto fetch = [&](int colbase) {
        const unsigned char* p = z + (size_t)(colbase + scol) * D + spart * 16;
#pragma unroll
        for (int j = 0; j < 4; j++) pf[j] = *(const int4*)(p + j * 64);
    };
    auto writeB = [&](int buf) {
#pragma unroll
        for (int j = 0; j < 4; j++)
            Bbuf[buf][(spart + 4 * j) * 64 + scol] = pf[j];
    };

    // ---- prologue ----
    int strip, colbase, cloc;
    decode(cb, strip, colbase, cloc);
    int curstrip = strip;
    fetch(colbase);
    writeB(0);
    loadA(strip);
    __syncthreads();

    for (int c = cb; c < ce; c++) {
        const int buf = (c - cb) & 1;
        decode(c, strip, colbase, cloc);

        const bool hn = (c + 1 < ce);
        if (hn) {
            int ns, ncb, ncl;
            decode(c + 1, ns, ncb, ncl);
            fetch(ncb);
        }
        if (strip != curstrip) {
            flushRs(curstrip);
            loadA(strip);
            curstrip = strip;
        }

#pragma unroll
        for (int mi = 0; mi < 2; mi++)
#pragma unroll
            for (int ni = 0; ni < 4; ni++)
                acc[mi][ni] = (floatx4){0.f, 0.f, 0.f, 0.f};

        const char* bbase = (const char*)Bbuf[buf];
#pragma unroll
        for (int kk = 0; kk < 8; kk++) {
            long long b[4];
#pragma unroll
            for (int ni = 0; ni < 4; ni++)
                b[ni] = *(const long long*)(
                    bbase + (((kk * 2 + (lg >> 1)) * 64 + ni * 16 + lm) * 16) +
                    (lg & 1) * 8);
#pragma unroll
            for (int mi = 0; mi < 2; mi++)
#pragma unroll
                for (int ni = 0; ni < 4; ni++)
                    acc[mi][ni] = __builtin_amdgcn_mfma_f32_16x16x32_fp8_fp8(
                        a[kk][mi], b[ni], acc[mi][ni], 0, 0, 0);
        }

        // ---- epilogue ----
        const bool diagreg = (cloc < 2);
        float cs[4] = {0.f, 0.f, 0.f, 0.f};
        if (diagreg) {
            const int rowb = strip * 128 + w * 32 + lg * 4;
#pragma unroll
            for (int mi = 0; mi < 2; mi++)
#pragma unroll
                for (int ni = 0; ni < 4; ni++) {
                    const int gcol = colbase + ni * 16 + lm;
#pragma unroll
                    for (int r = 0; r < 4; r++) {
                        int grow = rowb + mi * 16 + r;
                        float e = (grow == gcol) ? 0.f
                                                 : __expf(2.0f * acc[mi][ni][r]);
                        rsacc[mi][r] += e;
                    }
                }
        } else {
#pragma unroll
            for (int mi = 0; mi < 2; mi++)
#pragma unroll
                for (int ni = 0; ni < 4; ni++)
#pragma unroll
                    for (int r = 0; r < 4; r++) {
                        float e = __expf(2.0f * acc[mi][ni][r]);
                        rsacc[mi][r] += e;
                        cs[ni]      += e;
                    }
#pragma unroll
            for (int ni = 0; ni < 4; ni++) {
                float v = cs[ni];
                v += __shfl_xor(v, 16); v += __shfl_xor(v, 32);
                if (lane < 16)
                    atomicAdd(&rowsum[colbase + ni * 16 + lane], v);
            }
        }

        if (hn) {
            writeB(buf ^ 1);
            __syncthreads();
        }
    }
    flushRs(curstrip);

    // ---- last-block-done: final loss ----
    __syncthreads();
    if (tid == 0) {
        __threadfence();
        done_s = atomicAdd(counter, 1u);
    }
    __syncthreads();
    if (done_s == (unsigned int)(NBLK2 - 1)) {
        __threadfence();
        float acc_l = 0.f;
#pragma unroll 4
        for (int r = tid; r < NROWS; r += 256) {
            float rsv = __hip_atomic_load(&rowsum[r], __ATOMIC_RELAXED,
                                          __HIP_MEMORY_SCOPE_AGENT);
            acc_l += -2.0f * pos[r] + logf(rsv);
        }
#pragma unroll
        for (int off = 32; off > 0; off >>= 1) acc_l += __shfl_xor(acc_l, off);
        if (lane == 0) sdata[w] = acc_l;
        __syncthreads();
        if (tid == 0)
            out[0] = (sdata[0] + sdata[1] + sdata[2] + sdata[3]) / (float)NROWS;
    }
}

// ---------------------------------------------------------------------------
extern "C" void kernel_launch(void* const* d_in, const int* in_sizes, int n_in,
                              void* d_out, int out_size, void* d_ws, size_t ws_size,
                              hipStream_t stream) {
    const float* xi = (const float*)d_in[0];
    const float* xj = (const float*)d_in[1];
    float* out      = (float*)d_out;

    char* ws        = (char*)d_ws;
    unsigned char* z = (unsigned char*)ws;                    // 2 MiB (fp8)
    float* rowsum   = (float*)(ws + (size_t)NROWS * D);       // 32 KiB
    float* pos      = rowsum + NROWS;                         // 32 KiB
    unsigned int* counter = (unsigned int*)(pos + NROWS);

    norm_pos_kernel<<<B_ROWS / 4, 256, 0, stream>>>(xi, xj, z, pos,
                                                    rowsum, out, counter);
    sim_rowsum_kernel<<<NBLK2, 256, 0, stream>>>(z, rowsum, pos, counter, out);
}